// Round 5
// baseline (378.748 us; speedup 1.0000x reference)
//
#include <hip/hip_runtime.h>
#include <hip/hip_cooperative_groups.h>

namespace cg = cooperative_groups;

#define NN 50000
#define TOPK 32
#define IN_C 128
#define OUT_C 64
#define NEG_SLOPE 0.2f
#define BN_EPS 1e-5f

#define NTILE (NN / 16)           // phase-1: 3125 16-node tiles
#define NTASK (NN / 4)            // phase-2: 12500 4-node tasks
#define NVEC  (NN * OUT_C / 4)    // phase-4: 800000 float4

// workspace layout (floats)
#define WS_XBF   0                       // bf16 x_lin: NN*64*2B = NN*32 floats
#define WS_AI    (NN * 32)
#define WS_AJ    (WS_AI + NN)
#define WS_SUMS  (WS_AJ + NN)            // 128

__device__ inline float leaky(float a) { return a >= 0.f ? a : NEG_SLOPE * a; }
__device__ inline float bl(unsigned u) { return __uint_as_float(u << 16); }
__device__ inline float bh(unsigned u) { return __uint_as_float(u & 0xffff0000u); }

__device__ inline unsigned short f2bf(float f) {     // RNE fp32 -> bf16
    unsigned u = __float_as_uint(f);
    unsigned r = (u + 0x7fffu + ((u >> 16) & 1u)) >> 16;
    return (unsigned short)r;
}
__device__ inline unsigned pack2(float lo, float hi) {
    return (unsigned)f2bf(lo) | ((unsigned)f2bf(hi) << 16);
}

// Single cooperative kernel: linear+att coeffs | grid sync | attention
// aggregate + BN partials | grid sync | per-block BN stats + apply.
__global__ __launch_bounds__(256, 3) void gnn_fused(
    const float* __restrict__ x, const float* __restrict__ emb,
    const float* __restrict__ lin_w,
    const float* __restrict__ att_i, const float* __restrict__ att_j,
    const float* __restrict__ att_em_i, const float* __restrict__ att_em_j,
    const float* __restrict__ bias, const float* __restrict__ gamma,
    const float* __restrict__ beta, const int* __restrict__ src,
    float* __restrict__ ws, float* __restrict__ out)
{
    __shared__ float4 wt4[IN_C / 4 * OUT_C];   // 32 KB; aliased by BN bufs later
    __shared__ float2 vs[16][4];
    __shared__ float s_sc[64], s_sh[64];

    unsigned short* x_bf = (unsigned short*)(ws + WS_XBF);
    uint4* x_bf4 = (uint4*)x_bf;
    const uint2* x_bf2 = (const uint2*)x_bf;
    float* a_i  = ws + WS_AI;
    float* a_j  = ws + WS_AJ;
    float* sums = ws + WS_SUMS;

    const int tid = threadIdx.x;
    const int lane = tid & 63;
    const int wv = tid >> 6;

    if (blockIdx.x == 0 && tid < 128) sums[tid] = 0.f;

    // ================= phase 1: x_lin(bf16) + a_i/a_j =================
    {
        const float4* wg = (const float4*)lin_w;
#pragma unroll
        for (int i = 0; i < 8; ++i) wt4[tid + i * 256] = wg[tid + i * 256];
        __syncthreads();

        const int w = wv;              // channel quarter
        const int nl = lane >> 2;      // node within tile
        const int p = lane & 3;        // K sub-split (f4-interleaved)
        const float4* x4 = (const float4*)x;

        for (int tile = blockIdx.x; tile < NTILE; tile += gridDim.x) {
            const int n = tile * 16 + nl;
            float acc[16];
#pragma unroll
            for (int c = 0; c < 16; ++c) acc[c] = 0.f;

#pragma unroll
            for (int i = 0; i < 8; ++i) {
                const float4 xk = x4[n * 32 + i * 4 + p];
#pragma unroll
                for (int c = 0; c < 16; ++c) {
                    const float4 wvv = wt4[(w * 16 + c) * 32 + i * 4 + p];
                    acc[c] = fmaf(xk.x, wvv.x, acc[c]);
                    acc[c] = fmaf(xk.y, wvv.y, acc[c]);
                    acc[c] = fmaf(xk.z, wvv.z, acc[c]);
                    acc[c] = fmaf(xk.w, wvv.w, acc[c]);
                }
            }
#pragma unroll
            for (int c = 0; c < 16; ++c) {
                acc[c] += __shfl_xor(acc[c], 1, 64);
                acc[c] += __shfl_xor(acc[c], 2, 64);
            }

            if (p < 2) {               // bf16 store, 8 channels / lane
                uint4 pk;
                pk.x = pack2(p ? acc[8]  : acc[0], p ? acc[9]  : acc[1]);
                pk.y = pack2(p ? acc[10] : acc[2], p ? acc[11] : acc[3]);
                pk.z = pack2(p ? acc[12] : acc[4], p ? acc[13] : acc[5]);
                pk.w = pack2(p ? acc[14] : acc[6], p ? acc[15] : acc[7]);
                x_bf4[n * 8 + w * 2 + p] = pk;
            }

            const float4 e4   = ((const float4*)emb)[n * 16 + w * 4 + p];
            const float4 ai4  = ((const float4*)att_i)[w * 4 + p];
            const float4 aj4  = ((const float4*)att_j)[w * 4 + p];
            const float4 aei4 = ((const float4*)att_em_i)[w * 4 + p];
            const float4 aej4 = ((const float4*)att_em_j)[w * 4 + p];

            float sel[4];
#pragma unroll
            for (int j = 0; j < 4; ++j) {
                const float u = (p & 1) ? acc[4 + j] : acc[j];
                const float v = (p & 1) ? acc[12 + j] : acc[8 + j];
                sel[j] = (p & 2) ? v : u;          // = acc[p*4 + j]
            }
            float vi = sel[0] * ai4.x + e4.x * aei4.x;
            float vj = sel[0] * aj4.x + e4.x * aej4.x;
            vi += sel[1] * ai4.y + e4.y * aei4.y;  vj += sel[1] * aj4.y + e4.y * aej4.y;
            vi += sel[2] * ai4.z + e4.z * aei4.z;  vj += sel[2] * aj4.z + e4.z * aej4.z;
            vi += sel[3] * ai4.w + e4.w * aei4.w;  vj += sel[3] * aj4.w + e4.w * aej4.w;
            vi += __shfl_xor(vi, 1, 64); vi += __shfl_xor(vi, 2, 64);
            vj += __shfl_xor(vj, 1, 64); vj += __shfl_xor(vj, 2, 64);
            if (p == 0) vs[nl][w] = make_float2(vi, vj);
            __syncthreads();
            if (tid < 16) {
                const float si = vs[tid][0].x + vs[tid][1].x + vs[tid][2].x + vs[tid][3].x;
                const float sj = vs[tid][0].y + vs[tid][1].y + vs[tid][2].y + vs[tid][3].y;
                a_i[tile * 16 + tid] = si;
                a_j[tile * 16 + tid] = sj;
            }
            __syncthreads();
        }
    }

    __threadfence();
    cg::this_grid().sync();
    __threadfence();

    // ================= phase 2: attention aggregate + BN partials =========
    {
        const int g = lane >> 4;       // node within 4-node task
        const int q = lane & 15;       // row slice: channels q*4..q*4+3
        const float4 b4 = ((const float4*)bias)[q];
        float bs1[4] = {0.f, 0.f, 0.f, 0.f};
        float bs2[4] = {0.f, 0.f, 0.f, 0.f};

        for (int task = blockIdx.x * 4 + wv; task < NTASK; task += gridDim.x * 4) {
            const int t = task * 4 + g;
            const float ai_t = a_i[t];
            uint2 u[33];
            float alj[33];
            const int4* sp = (const int4*)(src + (size_t)t * TOPK);
            // issue all gathers up front: 33 row loads + 33 coeff loads
#pragma unroll
            for (int i = 0; i < 8; ++i) {
                const int4 s4 = sp[i];   // same addr for 16 lanes (broadcast)
                u[i * 4 + 0] = x_bf2[(size_t)s4.x * 16 + q];
                u[i * 4 + 1] = x_bf2[(size_t)s4.y * 16 + q];
                u[i * 4 + 2] = x_bf2[(size_t)s4.z * 16 + q];
                u[i * 4 + 3] = x_bf2[(size_t)s4.w * 16 + q];
                alj[i * 4 + 0] = a_j[s4.x];
                alj[i * 4 + 1] = a_j[s4.y];
                alj[i * 4 + 2] = a_j[s4.z];
                alj[i * 4 + 3] = a_j[s4.w];
            }
            u[32] = x_bf2[(size_t)t * 16 + q];
            alj[32] = a_j[t];

            // per-lane softmax over the 33 edges (no cross-lane ops)
            float m = -1e30f;
#pragma unroll
            for (int e = 0; e < 33; ++e) {
                alj[e] = leaky(ai_t + alj[e]);
                m = fmaxf(m, alj[e]);
            }
            float den = 0.f;
#pragma unroll
            for (int e = 0; e < 33; ++e) { alj[e] = __expf(alj[e] - m); den += alj[e]; }
            const float inv = 1.f / (den + 1e-16f);

            float A0 = 0.f, A1 = 0.f, A2 = 0.f, A3 = 0.f;
#pragma unroll
            for (int e = 0; e < 33; ++e) {
                const float we = alj[e] * inv;
                A0 = fmaf(we, bl(u[e].x), A0);
                A1 = fmaf(we, bh(u[e].x), A1);
                A2 = fmaf(we, bl(u[e].y), A2);
                A3 = fmaf(we, bh(u[e].y), A3);
            }
            const float v0 = A0 + b4.x, v1 = A1 + b4.y;
            const float v2 = A2 + b4.z, v3 = A3 + b4.w;
            ((float4*)out)[t * 16 + q] = make_float4(v0, v1, v2, v3);
            bs1[0] += v0; bs1[1] += v1; bs1[2] += v2; bs1[3] += v3;
            bs2[0] = fmaf(v0, v0, bs2[0]); bs2[1] = fmaf(v1, v1, bs2[1]);
            bs2[2] = fmaf(v2, v2, bs2[2]); bs2[3] = fmaf(v3, v3, bs2[3]);
        }

        // block BN reduction (alias wt4's LDS; phase-1 globally done)
        float (*sb1)[17] = (float(*)[17])wt4;
        float (*sb2)[17] = (float(*)[17])((char*)wt4 + 64 * 17 * 4);
        const int slot = wv * 4 + g;
        __syncthreads();
#pragma unroll
        for (int j = 0; j < 4; ++j) {
            sb1[q * 4 + j][slot] = bs1[j];
            sb2[q * 4 + j][slot] = bs2[j];
        }
        __syncthreads();
        if (tid < 64) {
            float t1 = 0.f, t2 = 0.f;
#pragma unroll
            for (int r = 0; r < 16; ++r) { t1 += sb1[tid][r]; t2 += sb2[tid][r]; }
            atomicAdd(&sums[tid], t1);
            atomicAdd(&sums[64 + tid], t2);
        }
    }

    __threadfence();
    cg::this_grid().sync();
    __threadfence();

    // ============ phase 3+4: BN stats (per block) + apply + ReLU ==========
    if (tid < 64) {
        const float mu = sums[tid] / (float)NN;
        const float ex2 = sums[64 + tid] / (float)NN;
        const float var = fmaxf(ex2 - mu * mu, 0.f);
        const float sc = gamma[tid] / sqrtf(var + BN_EPS);
        s_sc[tid] = sc;
        s_sh[tid] = beta[tid] - mu * sc;
    }
    __syncthreads();
    float4* o4 = (float4*)out;
    for (int idx = blockIdx.x * 256 + tid; idx < NVEC; idx += gridDim.x * 256) {
        float4 v = o4[idx];
        const int c0 = (idx & 15) * 4;
        v.x = fmaxf(fmaf(v.x, s_sc[c0 + 0], s_sh[c0 + 0]), 0.f);
        v.y = fmaxf(fmaf(v.y, s_sc[c0 + 1], s_sh[c0 + 1]), 0.f);
        v.z = fmaxf(fmaf(v.z, s_sc[c0 + 2], s_sh[c0 + 2]), 0.f);
        v.w = fmaxf(fmaf(v.w, s_sc[c0 + 3], s_sh[c0 + 3]), 0.f);
        o4[idx] = v;
    }
}

extern "C" void kernel_launch(void* const* d_in, const int* in_sizes, int n_in,
                              void* d_out, int out_size, void* d_ws, size_t ws_size,
                              hipStream_t stream) {
    const float* x        = (const float*)d_in[0];
    const float* emb      = (const float*)d_in[1];
    const int*   edge     = (const int*)d_in[2];   // row 0 = src
    const float* lin_w    = (const float*)d_in[3];
    const float* att_i    = (const float*)d_in[4];
    const float* att_j    = (const float*)d_in[5];
    const float* att_em_i = (const float*)d_in[6];
    const float* att_em_j = (const float*)d_in[7];
    const float* bias     = (const float*)d_in[8];
    const float* gamma    = (const float*)d_in[9];
    const float* beta     = (const float*)d_in[10];
    float* ws  = (float*)d_ws;
    float* out = (float*)d_out;

    int nb = 0;
    hipOccupancyMaxActiveBlocksPerMultiprocessor(&nb, gnn_fused, 256, 0);
    if (nb < 1) nb = 1;
    int grid = nb * 256;              // 256 CUs on MI355X
    if (grid > 1024) grid = 1024;

    void* args[] = {
        (void*)&x, (void*)&emb, (void*)&lin_w,
        (void*)&att_i, (void*)&att_j, (void*)&att_em_i, (void*)&att_em_j,
        (void*)&bias, (void*)&gamma, (void*)&beta, (void*)&edge,
        (void*)&ws, (void*)&out
    };
    hipLaunchCooperativeKernel((void*)gnn_fused, dim3(grid), dim3(256),
                               args, 0, stream);
}

// Round 6
// 357.364 us; speedup vs baseline: 1.0598x; 1.0598x over previous
//
#include <hip/hip_runtime.h>

#define NN 50000
#define TOPK 32
#define IN_C 128
#define OUT_C 64
#define NEG_SLOPE 0.2f
#define BN_EPS 1e-5f

// K1: 40-node tile per block, 10 nodes per wave, weights in VGPRs
#define K1_NB 40
#define K1_NPW 10
#define K1_BLOCKS (NN / K1_NB)      // 1250

// K2: 4 nodes per wave-task, 2 tasks per wave
#define NTASK (NN / 4)              // 12500
#define K2_WAVES (NTASK / 2)        // 6250
#define K2_BLOCKS ((K2_WAVES + 3) / 4)  // 1563

// workspace layout (floats)
#define WS_XBF   0                       // bf16 x_lin: NN*64*2B
#define WS_AI    (NN * 32)
#define WS_AJ    (WS_AI + NN)
#define WS_SUMS  (WS_AJ + NN)            // 128

__device__ inline float leaky(float a) { return a >= 0.f ? a : NEG_SLOPE * a; }
__device__ inline float bl(unsigned u) { return __uint_as_float(u << 16); }
__device__ inline float bh(unsigned u) { return __uint_as_float(u & 0xffff0000u); }

__device__ inline unsigned short f2bf(float f) {     // RNE fp32 -> bf16
    unsigned u = __float_as_uint(f);
    unsigned r = (u + 0x7fffu + ((u >> 16) & 1u)) >> 16;
    return (unsigned short)r;
}

// K1: x_lin(bf16) = x @ lin_w^T + attention coefficients a_i/a_j.
// Lane = output channel. Weight row stationary in VGPRs (32 f4 = 128 regs,
// loaded once per block). x tile staged to LDS coalesced, consumed as
// same-address broadcast ds_read_b128 (conflict-free). 4 FMAs per LDS
// read per lane; 2-node ILP in the K loop.
__global__ __launch_bounds__(256, 3) void k1_linear(
    const float* __restrict__ x, const float* __restrict__ emb,
    const float* __restrict__ lin_w,
    const float* __restrict__ att_i, const float* __restrict__ att_j,
    const float* __restrict__ att_em_i, const float* __restrict__ att_em_j,
    unsigned short* __restrict__ x_bf, float* __restrict__ a_i,
    float* __restrict__ a_j, float* __restrict__ sums)
{
    __shared__ float4 xs4[K1_NB * 32];     // 40 rows x 128 floats = 20 KB
    const int tid = threadIdx.x;
    if (blockIdx.x == 0 && tid < 128) sums[tid] = 0.f;   // K2 runs after K1

    const int base = blockIdx.x * K1_NB;
    const float4* xg = (const float4*)(x + (size_t)base * IN_C);
#pragma unroll
    for (int i = 0; i < (K1_NB * 32) / 256; ++i)         // 5 f4/thread
        xs4[tid + i * 256] = xg[tid + i * 256];

    const int lane = tid & 63;
    const int j0 = (tid >> 6) * K1_NPW;    // this wave's first local node

    // weight row for this lane's channel -> VGPRs
    float4 wr4[32];
    {
        const float4* wrow = (const float4*)(lin_w + lane * IN_C);
#pragma unroll
        for (int i = 0; i < 32; ++i) wr4[i] = wrow[i];
    }
    const float ai_c = att_i[lane], aj_c = att_j[lane];
    const float aei_c = att_em_i[lane], aej_c = att_em_j[lane];
    __syncthreads();

    for (int j = 0; j < K1_NPW; j += 2) {
        const float4* xr0 = xs4 + (j0 + j) * 32;
        const float4* xr1 = xr0 + 32;
        float a0 = 0.f, a1 = 0.f;
#pragma unroll
        for (int k4 = 0; k4 < 32; ++k4) {
            const float4 w4 = wr4[k4];
            const float4 x0 = xr0[k4];     // same addr all 64 lanes: broadcast
            const float4 x1 = xr1[k4];
            a0 = fmaf(w4.x, x0.x, a0); a1 = fmaf(w4.x, x1.x, a1);
            a0 = fmaf(w4.y, x0.y, a0); a1 = fmaf(w4.y, x1.y, a1);
            a0 = fmaf(w4.z, x0.z, a0); a1 = fmaf(w4.z, x1.z, a1);
            a0 = fmaf(w4.w, x0.w, a0); a1 = fmaf(w4.w, x1.w, a1);
        }
#pragma unroll
        for (int h = 0; h < 2; ++h) {
            const int n = base + j0 + j + h;
            const float y = h ? a1 : a0;
            x_bf[(size_t)n * OUT_C + lane] = f2bf(y);
            const float e = emb[(size_t)n * OUT_C + lane];
            float vi = fmaf(y, ai_c, e * aei_c);
            float vj = fmaf(y, aj_c, e * aej_c);
#pragma unroll
            for (int d = 1; d < 64; d <<= 1) {
                vi += __shfl_xor(vi, d, 64);
                vj += __shfl_xor(vj, d, 64);
            }
            if (lane == 0) { a_i[n] = vi; a_j[n] = vj; }
        }
    }
}

// K2: 4 nodes per wave-task (16 lanes/node, lane owns 4 channels), 2 tasks
// per wave. Softmax computed redundantly per lane from broadcast loads (no
// cross-lane ops, no shuffle->load chains). s4[8]+alj[33] kept in regs
// (~75 VGPR, no spill); gathers issue in 8 independent 4-wide groups.
__global__ __launch_bounds__(256, 4) void k2_attn(
    const int* __restrict__ src,
    const uint2* __restrict__ x_bf2, const float* __restrict__ a_i,
    const float* __restrict__ a_j, const float* __restrict__ bias,
    float* __restrict__ out, float* __restrict__ sums)
{
    const int tid = threadIdx.x;
    const int lane = tid & 63;
    const int wv = tid >> 6;
    const int wavei = blockIdx.x * 4 + wv;
    const int g = lane >> 4;
    const int q = lane & 15;
    const float4 b4 = ((const float4*)bias)[q];

    float bs1[4] = {0.f, 0.f, 0.f, 0.f};
    float bs2[4] = {0.f, 0.f, 0.f, 0.f};

    if (wavei < K2_WAVES) {
#pragma unroll
        for (int r = 0; r < 2; ++r) {
            const int task = wavei + r * K2_WAVES;
            const int t = task * 4 + g;
            const float ai_t = a_i[t];
            const int4* sp4 = (const int4*)(src + (size_t)t * TOPK);

            int4 s4[8];
#pragma unroll
            for (int i = 0; i < 8; ++i) s4[i] = sp4[i];   // broadcast (16 lanes)

            float alj[33];
#pragma unroll
            for (int i = 0; i < 8; ++i) {                 // 32 independent loads
                alj[i * 4 + 0] = a_j[s4[i].x];
                alj[i * 4 + 1] = a_j[s4[i].y];
                alj[i * 4 + 2] = a_j[s4[i].z];
                alj[i * 4 + 3] = a_j[s4[i].w];
            }
            alj[32] = a_j[t];                             // self edge

            float mx = -1e30f;
#pragma unroll
            for (int e = 0; e < 33; ++e) {
                alj[e] = leaky(ai_t + alj[e]);
                mx = fmaxf(mx, alj[e]);
            }
            float den = 0.f;
#pragma unroll
            for (int e = 0; e < 33; ++e) { alj[e] = __expf(alj[e] - mx); den += alj[e]; }
            const float inv = 1.f / (den + 1e-16f);

            float A0 = 0.f, A1 = 0.f, A2 = 0.f, A3 = 0.f;
#define ACC4(U, W)                                                            \
            { A0 = fmaf(W, bl(U.x), A0); A1 = fmaf(W, bh(U.x), A1);           \
              A2 = fmaf(W, bl(U.y), A2); A3 = fmaf(W, bh(U.y), A3); }
#pragma unroll
            for (int i = 0; i < 8; ++i) {                 // 4 indep gathers/group
                const uint2 u0 = x_bf2[(size_t)s4[i].x * 16 + q];
                const uint2 u1 = x_bf2[(size_t)s4[i].y * 16 + q];
                const uint2 u2 = x_bf2[(size_t)s4[i].z * 16 + q];
                const uint2 u3 = x_bf2[(size_t)s4[i].w * 16 + q];
                const float w0 = alj[i * 4 + 0] * inv;
                const float w1 = alj[i * 4 + 1] * inv;
                const float w2 = alj[i * 4 + 2] * inv;
                const float w3 = alj[i * 4 + 3] * inv;
                ACC4(u0, w0); ACC4(u1, w1); ACC4(u2, w2); ACC4(u3, w3);
            }
            {
                const uint2 us = x_bf2[(size_t)t * 16 + q];
                const float wsf = alj[32] * inv;
                ACC4(us, wsf);
            }
#undef ACC4
            const float v0 = A0 + b4.x, v1 = A1 + b4.y;
            const float v2 = A2 + b4.z, v3 = A3 + b4.w;
            ((float4*)out)[t * 16 + q] = make_float4(v0, v1, v2, v3);
            bs1[0] += v0; bs1[1] += v1; bs1[2] += v2; bs1[3] += v3;
            bs2[0] = fmaf(v0, v0, bs2[0]); bs2[1] = fmaf(v1, v1, bs2[1]);
            bs2[2] = fmaf(v2, v2, bs2[2]); bs2[3] = fmaf(v3, v3, bs2[3]);
        }
    }

    // block BN reduction: channel c = q*4+j, slot = wv*4+g (16 slots)
    __shared__ float sb1[64][17];
    __shared__ float sb2[64][17];
    const int slot = wv * 4 + g;
#pragma unroll
    for (int j = 0; j < 4; ++j) {
        sb1[q * 4 + j][slot] = bs1[j];
        sb2[q * 4 + j][slot] = bs2[j];
    }
    __syncthreads();
    if (tid < 64) {
        float t1 = 0.f, t2 = 0.f;
#pragma unroll
        for (int rr = 0; rr < 16; ++rr) { t1 += sb1[tid][rr]; t2 += sb2[tid][rr]; }
        atomicAdd(&sums[tid], t1);
        atomicAdd(&sums[64 + tid], t2);
    }
}

// K4: BN stats computed redundantly per block from sums, then apply + ReLU.
__global__ __launch_bounds__(256) void k4_bn(
    float* __restrict__ out, const float* __restrict__ sums,
    const float* __restrict__ gamma, const float* __restrict__ beta)
{
    __shared__ float s_sc[64], s_sh[64];
    const int tid = threadIdx.x;
    if (tid < 64) {
        const float mu = sums[tid] / (float)NN;
        const float ex2 = sums[64 + tid] / (float)NN;
        const float var = fmaxf(ex2 - mu * mu, 0.f);
        const float sc = gamma[tid] / sqrtf(var + BN_EPS);
        s_sc[tid] = sc;
        s_sh[tid] = beta[tid] - mu * sc;
    }
    __syncthreads();
    const int total = NN * OUT_C / 4;
    float4* p = (float4*)out;
    for (int idx = blockIdx.x * 256 + tid; idx < total; idx += gridDim.x * 256) {
        float4 v = p[idx];
        const int c0 = (idx & 15) * 4;
        v.x = fmaxf(fmaf(v.x, s_sc[c0 + 0], s_sh[c0 + 0]), 0.f);
        v.y = fmaxf(fmaf(v.y, s_sc[c0 + 1], s_sh[c0 + 1]), 0.f);
        v.z = fmaxf(fmaf(v.z, s_sc[c0 + 2], s_sh[c0 + 2]), 0.f);
        v.w = fmaxf(fmaf(v.w, s_sc[c0 + 3], s_sh[c0 + 3]), 0.f);
        p[idx] = v;
    }
}

extern "C" void kernel_launch(void* const* d_in, const int* in_sizes, int n_in,
                              void* d_out, int out_size, void* d_ws, size_t ws_size,
                              hipStream_t stream) {
    const float* x        = (const float*)d_in[0];
    const float* emb      = (const float*)d_in[1];
    const int*   edge     = (const int*)d_in[2];   // row 0 = src
    const float* lin_w    = (const float*)d_in[3];
    const float* att_i    = (const float*)d_in[4];
    const float* att_j    = (const float*)d_in[5];
    const float* att_em_i = (const float*)d_in[6];
    const float* att_em_j = (const float*)d_in[7];
    const float* bias     = (const float*)d_in[8];
    const float* gamma    = (const float*)d_in[9];
    const float* beta     = (const float*)d_in[10];

    float* ws    = (float*)d_ws;
    unsigned short* x_bf = (unsigned short*)(ws + WS_XBF);
    float* a_i   = ws + WS_AI;
    float* a_j   = ws + WS_AJ;
    float* sums  = ws + WS_SUMS;
    float* out   = (float*)d_out;

    k1_linear<<<K1_BLOCKS, 256, 0, stream>>>(x, emb, lin_w, att_i, att_j,
                                             att_em_i, att_em_j, x_bf, a_i, a_j, sums);
    k2_attn<<<K2_BLOCKS, 256, 0, stream>>>(edge, (const uint2*)x_bf, a_i, a_j,
                                           bias, out, sums);
    k4_bn<<<1024, 256, 0, stream>>>(out, sums, gamma, beta);
}

// Round 7
// 178.060 us; speedup vs baseline: 2.1271x; 2.0070x over previous
//
#include <hip/hip_runtime.h>

#define NN 50000
#define TOPK 32
#define IN_C 128
#define OUT_C 64
#define NEG_SLOPE 0.2f
#define BN_EPS 1e-5f

// K1: MFMA, 16 nodes per block, wave = 16-channel slice
#define K1_BLOCKS (NN / 16)         // 3125

// K2: 4 nodes per wave-task, 2 tasks per wave (frozen from round 6)
#define NTASK (NN / 4)              // 12500
#define K2_WAVES (NTASK / 2)        // 6250
#define K2_BLOCKS ((K2_WAVES + 3) / 4)  // 1563

// workspace layout (floats)
#define WS_XBF   0                       // bf16 x_lin: NN*64*2B
#define WS_AI    (NN * 32)
#define WS_AJ    (WS_AI + NN)
#define WS_SUMS  (WS_AJ + NN)            // 128

typedef __bf16 bf16x8 __attribute__((ext_vector_type(8)));
typedef float f32x4 __attribute__((ext_vector_type(4)));
union BF8 { unsigned short u[8]; bf16x8 v; };

__device__ inline float leaky(float a) { return a >= 0.f ? a : NEG_SLOPE * a; }
__device__ inline float bl(unsigned u) { return __uint_as_float(u << 16); }
__device__ inline float bh(unsigned u) { return __uint_as_float(u & 0xffff0000u); }

__device__ inline unsigned short f2bf(float f) {     // RNE fp32 -> bf16
    unsigned u = __float_as_uint(f);
    unsigned r = (u + 0x7fffu + ((u >> 16) & 1u)) >> 16;
    return (unsigned short)r;
}

// K1: x_lin(bf16) = x @ lin_w^T via MFMA 16x16x32_bf16 + a_i/a_j epilogue.
// A = x tile (m=node), B = lin_w rows (n=channel, B^T layout as stored).
// A-frag: A[m=lane&15][k=(lane>>4)*8+j]; C/D: col(lane&15)=n, row=quad*4+reg.
// No LDS staging: frags converted in registers from coalesced global loads.
__global__ __launch_bounds__(256) void k1_mfma(
    const float* __restrict__ x, const float* __restrict__ emb,
    const float* __restrict__ lin_w,
    const float* __restrict__ att_i, const float* __restrict__ att_j,
    const float* __restrict__ att_em_i, const float* __restrict__ att_em_j,
    unsigned short* __restrict__ x_bf, float* __restrict__ a_i,
    float* __restrict__ a_j, float* __restrict__ sums)
{
    __shared__ float redi[16][5], redj[16][5];
    __shared__ float eredi[16][17], eredj[16][17];
    const int tid = threadIdx.x;
    if (blockIdx.x == 0 && tid < 128) sums[tid] = 0.f;   // K2 runs after K1

    const int lane = tid & 63;
    const int wv = tid >> 6;
    const int quad = lane >> 4;
    const int nn = lane & 15;
    const int base = blockIdx.x * 16;
    const int c = wv * 16 + nn;          // this lane's output channel

    BF8 bfr[4], afr[4];
    {
        const float* wr = lin_w + (size_t)c * IN_C + quad * 8;
        const float* xr = x + (size_t)(base + nn) * IN_C + quad * 8;
#pragma unroll
        for (int s = 0; s < 4; ++s) {
            const float4 wa = *(const float4*)(wr + s * 32);
            const float4 wb = *(const float4*)(wr + s * 32 + 4);
            const float4 xa = *(const float4*)(xr + s * 32);
            const float4 xb = *(const float4*)(xr + s * 32 + 4);
            bfr[s].u[0] = f2bf(wa.x); bfr[s].u[1] = f2bf(wa.y);
            bfr[s].u[2] = f2bf(wa.z); bfr[s].u[3] = f2bf(wa.w);
            bfr[s].u[4] = f2bf(wb.x); bfr[s].u[5] = f2bf(wb.y);
            bfr[s].u[6] = f2bf(wb.z); bfr[s].u[7] = f2bf(wb.w);
            afr[s].u[0] = f2bf(xa.x); afr[s].u[1] = f2bf(xa.y);
            afr[s].u[2] = f2bf(xa.z); afr[s].u[3] = f2bf(xa.w);
            afr[s].u[4] = f2bf(xb.x); afr[s].u[5] = f2bf(xb.y);
            afr[s].u[6] = f2bf(xb.z); afr[s].u[7] = f2bf(xb.w);
        }
    }

    f32x4 acc = {0.f, 0.f, 0.f, 0.f};
#pragma unroll
    for (int s = 0; s < 4; ++s)
        acc = __builtin_amdgcn_mfma_f32_16x16x32_bf16(afr[s].v, bfr[s].v, acc,
                                                      0, 0, 0);

    // epilogue: x_lin store + attention partials (reduce over channels)
    const float aic = att_i[c], ajc = att_j[c];
    float pi[4], pj[4];
#pragma unroll
    for (int r = 0; r < 4; ++r) {
        const int node = base + quad * 4 + r;
        x_bf[(size_t)node * OUT_C + c] = f2bf(acc[r]);
        pi[r] = acc[r] * aic;
        pj[r] = acc[r] * ajc;
    }
#pragma unroll
    for (int d = 1; d < 16; d <<= 1) {
#pragma unroll
        for (int r = 0; r < 4; ++r) {
            pi[r] += __shfl_xor(pi[r], d, 64);
            pj[r] += __shfl_xor(pj[r], d, 64);
        }
    }
    if (nn == 0) {
#pragma unroll
        for (int r = 0; r < 4; ++r) {
            redi[quad * 4 + r][wv] = pi[r];
            redj[quad * 4 + r][wv] = pj[r];
        }
    }

    // emb contributions: thread t -> node t>>4, channel-quad t&15
    {
        const int nl = tid >> 4, c4 = tid & 15;
        const float4 e4 = ((const float4*)emb)[(size_t)(base + nl) * 16 + c4];
        const float4 i4 = ((const float4*)att_em_i)[c4];
        const float4 j4 = ((const float4*)att_em_j)[c4];
        eredi[nl][c4] = e4.x * i4.x + e4.y * i4.y + e4.z * i4.z + e4.w * i4.w;
        eredj[nl][c4] = e4.x * j4.x + e4.y * j4.y + e4.z * j4.z + e4.w * j4.w;
    }
    __syncthreads();
    if (tid < 16) {
        float si = redi[tid][0] + redi[tid][1] + redi[tid][2] + redi[tid][3];
        float sj = redj[tid][0] + redj[tid][1] + redj[tid][2] + redj[tid][3];
#pragma unroll
        for (int r = 0; r < 16; ++r) { si += eredi[tid][r]; sj += eredj[tid][r]; }
        a_i[base + tid] = si;
        a_j[base + tid] = sj;
    }
}

// K2 (frozen from round 6): 4 nodes per wave-task, 2 tasks per wave.
__global__ __launch_bounds__(256, 4) void k2_attn(
    const int* __restrict__ src,
    const uint2* __restrict__ x_bf2, const float* __restrict__ a_i,
    const float* __restrict__ a_j, const float* __restrict__ bias,
    float* __restrict__ out, float* __restrict__ sums)
{
    const int tid = threadIdx.x;
    const int lane = tid & 63;
    const int wv = tid >> 6;
    const int wavei = blockIdx.x * 4 + wv;
    const int g = lane >> 4;
    const int q = lane & 15;
    const float4 b4 = ((const float4*)bias)[q];

    float bs1[4] = {0.f, 0.f, 0.f, 0.f};
    float bs2[4] = {0.f, 0.f, 0.f, 0.f};

    if (wavei < K2_WAVES) {
#pragma unroll
        for (int r = 0; r < 2; ++r) {
            const int task = wavei + r * K2_WAVES;
            const int t = task * 4 + g;
            const float ai_t = a_i[t];
            const int4* sp4 = (const int4*)(src + (size_t)t * TOPK);

            int4 s4[8];
#pragma unroll
            for (int i = 0; i < 8; ++i) s4[i] = sp4[i];

            float alj[33];
#pragma unroll
            for (int i = 0; i < 8; ++i) {
                alj[i * 4 + 0] = a_j[s4[i].x];
                alj[i * 4 + 1] = a_j[s4[i].y];
                alj[i * 4 + 2] = a_j[s4[i].z];
                alj[i * 4 + 3] = a_j[s4[i].w];
            }
            alj[32] = a_j[t];

            float mx = -1e30f;
#pragma unroll
            for (int e = 0; e < 33; ++e) {
                alj[e] = leaky(ai_t + alj[e]);
                mx = fmaxf(mx, alj[e]);
            }
            float den = 0.f;
#pragma unroll
            for (int e = 0; e < 33; ++e) { alj[e] = __expf(alj[e] - mx); den += alj[e]; }
            const float inv = 1.f / (den + 1e-16f);

            float A0 = 0.f, A1 = 0.f, A2 = 0.f, A3 = 0.f;
#define ACC4(U, W)                                                            \
            { A0 = fmaf(W, bl(U.x), A0); A1 = fmaf(W, bh(U.x), A1);           \
              A2 = fmaf(W, bl(U.y), A2); A3 = fmaf(W, bh(U.y), A3); }
#pragma unroll
            for (int i = 0; i < 8; ++i) {
                const uint2 u0 = x_bf2[(size_t)s4[i].x * 16 + q];
                const uint2 u1 = x_bf2[(size_t)s4[i].y * 16 + q];
                const uint2 u2 = x_bf2[(size_t)s4[i].z * 16 + q];
                const uint2 u3 = x_bf2[(size_t)s4[i].w * 16 + q];
                const float w0 = alj[i * 4 + 0] * inv;
                const float w1 = alj[i * 4 + 1] * inv;
                const float w2 = alj[i * 4 + 2] * inv;
                const float w3 = alj[i * 4 + 3] * inv;
                ACC4(u0, w0); ACC4(u1, w1); ACC4(u2, w2); ACC4(u3, w3);
            }
            {
                const uint2 us = x_bf2[(size_t)t * 16 + q];
                const float wsf = alj[32] * inv;
                ACC4(us, wsf);
            }
#undef ACC4
            const float v0 = A0 + b4.x, v1 = A1 + b4.y;
            const float v2 = A2 + b4.z, v3 = A3 + b4.w;
            ((float4*)out)[t * 16 + q] = make_float4(v0, v1, v2, v3);
            bs1[0] += v0; bs1[1] += v1; bs1[2] += v2; bs1[3] += v3;
            bs2[0] = fmaf(v0, v0, bs2[0]); bs2[1] = fmaf(v1, v1, bs2[1]);
            bs2[2] = fmaf(v2, v2, bs2[2]); bs2[3] = fmaf(v3, v3, bs2[3]);
        }
    }

    __shared__ float sb1[64][17];
    __shared__ float sb2[64][17];
    const int slot = wv * 4 + g;
#pragma unroll
    for (int j = 0; j < 4; ++j) {
        sb1[q * 4 + j][slot] = bs1[j];
        sb2[q * 4 + j][slot] = bs2[j];
    }
    __syncthreads();
    if (tid < 64) {
        float t1 = 0.f, t2 = 0.f;
#pragma unroll
        for (int rr = 0; rr < 16; ++rr) { t1 += sb1[tid][rr]; t2 += sb2[tid][rr]; }
        atomicAdd(&sums[tid], t1);
        atomicAdd(&sums[64 + tid], t2);
    }
}

// K4: BN stats computed redundantly per block from sums, then apply + ReLU.
__global__ __launch_bounds__(256) void k4_bn(
    float* __restrict__ out, const float* __restrict__ sums,
    const float* __restrict__ gamma, const float* __restrict__ beta)
{
    __shared__ float s_sc[64], s_sh[64];
    const int tid = threadIdx.x;
    if (tid < 64) {
        const float mu = sums[tid] / (float)NN;
        const float ex2 = sums[64 + tid] / (float)NN;
        const float var = fmaxf(ex2 - mu * mu, 0.f);
        const float sc = gamma[tid] / sqrtf(var + BN_EPS);
        s_sc[tid] = sc;
        s_sh[tid] = beta[tid] - mu * sc;
    }
    __syncthreads();
    const int total = NN * OUT_C / 4;
    float4* p = (float4*)out;
    for (int idx = blockIdx.x * 256 + tid; idx < total; idx += gridDim.x * 256) {
        float4 v = p[idx];
        const int c0 = (idx & 15) * 4;
        v.x = fmaxf(fmaf(v.x, s_sc[c0 + 0], s_sh[c0 + 0]), 0.f);
        v.y = fmaxf(fmaf(v.y, s_sc[c0 + 1], s_sh[c0 + 1]), 0.f);
        v.z = fmaxf(fmaf(v.z, s_sc[c0 + 2], s_sh[c0 + 2]), 0.f);
        v.w = fmaxf(fmaf(v.w, s_sc[c0 + 3], s_sh[c0 + 3]), 0.f);
        p[idx] = v;
    }
}

extern "C" void kernel_launch(void* const* d_in, const int* in_sizes, int n_in,
                              void* d_out, int out_size, void* d_ws, size_t ws_size,
                              hipStream_t stream) {
    const float* x        = (const float*)d_in[0];
    const float* emb      = (const float*)d_in[1];
    const int*   edge     = (const int*)d_in[2];   // row 0 = src
    const float* lin_w    = (const float*)d_in[3];
    const float* att_i    = (const float*)d_in[4];
    const float* att_j    = (const float*)d_in[5];
    const float* att_em_i = (const float*)d_in[6];
    const float* att_em_j = (const float*)d_in[7];
    const float* bias     = (const float*)d_in[8];
    const float* gamma    = (const float*)d_in[9];
    const float* beta     = (const float*)d_in[10];

    float* ws    = (float*)d_ws;
    unsigned short* x_bf = (unsigned short*)(ws + WS_XBF);
    float* a_i   = ws + WS_AI;
    float* a_j   = ws + WS_AJ;
    float* sums  = ws + WS_SUMS;
    float* out   = (float*)d_out;

    k1_mfma<<<K1_BLOCKS, 256, 0, stream>>>(x, emb, lin_w, att_i, att_j,
                                           att_em_i, att_em_j, x_bf, a_i, a_j, sums);
    k2_attn<<<K2_BLOCKS, 256, 0, stream>>>(edge, (const uint2*)x_bf, a_i, a_j,
                                           bias, out, sums);
    k4_bn<<<1024, 256, 0, stream>>>(out, sums, gamma, beta);
}